// Round 13
// baseline (87.079 us; speedup 1.0000x reference)
//
#include <hip/hip_runtime.h>

#define L_TOK 4096
#define D_DIM 2048
#define R_STEPS 10
#define G_TOK 410
#define NROWS 1640
#define FB_NBLK 256

typedef unsigned int uint;
typedef unsigned long long u64;

// ws layout (bytes), zeroed each call:
// [0,1280)     flagset[r*32]  (speculative kernel's computed flags, stride 128B)
// [2048,3328)  flags2[r*32]   (fallback's exact flags)
// [3968,3976)  barrier {count, generation}

__device__ __forceinline__ void load8(float* v, const float* p) {
  float4 a = *(const float4*)p;
  float4 b = *(const float4*)(p + 4);
  v[0] = a.x; v[1] = a.y; v[2] = a.z; v[3] = a.w;
  v[4] = b.x; v[5] = b.y; v[6] = b.z; v[7] = b.w;
}
__device__ __forceinline__ void zero8(float* v) {
#pragma unroll
  for (int i = 0; i < 8; ++i) v[i] = 0.0f;
}
__device__ __forceinline__ void store8(float* p, const float* v) {
  *(float4*)p = make_float4(v[0], v[1], v[2], v[3]);
  *(float4*)(p + 4) = make_float4(v[4], v[5], v[6], v[7]);
}

// ---------------- speculative kernel: assume every step's flag == 1 ----------------
// WAVE-PER-ROW: one 64-lane wave owns one row (32 elems/lane). No LDS, no
// __syncthreads, no spin-gate — reductions are 6-level __shfl_xor butterflies
// (every lane gets the block... wave total). Independent instruction streams
// per CU: 4 (block-lockstep, R6-R12 plateau at ~80us) -> 16 free-running waves,
// hiding each other's reduce->sqrt->divide dependent chains.
// Coalescing: lane reads float4 at lane*4 + k*256; each k covers 1KB contiguous.
__global__ __launch_bounds__(256, 2) void qact_spec(
    const float* __restrict__ x, const float* __restrict__ s,
    float* __restrict__ y, uint* __restrict__ flagset) {
  const int lane = threadIdx.x & 63, wid = threadIdx.x >> 6;
  const int row = blockIdx.x * 4 + wid;           // 410 blocks x 4 waves = 1640 rows
  const int b = row / G_TOK, g = row % G_TOK;
  const size_t base = ((size_t)b * L_TOK + (size_t)g * R_STEPS) * D_DIM + (size_t)lane * 4;

  uint m = 0;  // this lane's 32 outlier-mask bits (carried across steps)
  float cur[32], nxt[32];
#pragma unroll
  for (int k = 0; k < 8; ++k) {  // token g*10 always < 4096
    const float4 v = *(const float4*)(x + base + k * 256);
    cur[k * 4 + 0] = v.x; cur[k * 4 + 1] = v.y;
    cur[k * 4 + 2] = v.z; cur[k * 4 + 3] = v.w;
  }

  for (int r = 0; r < R_STEPS; ++r) {
    const int tok = g * R_STEPS + r;
    const bool valid = tok < L_TOK;  // wave-uniform
    const float sv = valid ? s[tok] : 1.0f;

    // prefetch next token slab — no barrier anywhere to drain it early
    if (r + 1 < R_STEPS) {
      if (tok + 1 < L_TOK) {
#pragma unroll
        for (int k = 0; k < 8; ++k) {
          const float4 v = *(const float4*)(x + base + (size_t)(r + 1) * D_DIM + k * 256);
          nxt[k * 4 + 0] = v.x; nxt[k * 4 + 1] = v.y;
          nxt[k * 4 + 2] = v.z; nxt[k * 4 + 3] = v.w;
        }
      } else {
#pragma unroll
        for (int i = 0; i < 32; ++i) nxt[i] = 0.0f;
      }
    }

    // ---- fused reduction: A=max|x| unmasked, Bm=max|x| masked, S1/S2 fp64 sums ----
    float A = 0.0f, Bm = 0.0f;
    double S1 = 0.0, S2 = 0.0;
#pragma unroll
    for (int i = 0; i < 32; ++i) {
      const bool bit = (m >> i) & 1u;
      const float fa = fabsf(cur[i]);
      const float ai = bit ? 0.0f : fa;
      A = fmaxf(A, ai);
      Bm = bit ? fmaxf(Bm, fa) : Bm;
      const double ad = (double)ai;
      S1 += ad;
      S2 += ad * ad;
    }
    // butterfly: all 64 lanes end with the wave-wide result (replaces LDS broadcast)
#pragma unroll
    for (int o = 1; o < 64; o <<= 1) {
      A = fmaxf(A, __shfl_xor(A, o, 64));
      Bm = fmaxf(Bm, __shfl_xor(Bm, o, 64));
      S1 += __shfl_xor(S1, o, 64);
      S2 += __shfl_xor(S2, o, 64);
    }

    if (lane == 0) {
      if (A / 7.0f > sv) atomicOr(&flagset[r * 32], 1u);  // record exact contribution
    }

    // ---- mask update under flag=1 assumption: a > mean + 3*std(ddof=1) ----
    const double n = (double)D_DIM;
    const double mean = S1 / n;
    double var = (S2 - n * mean * mean) / (n - 1.0);
    var = var > 0.0 ? var : 0.0;
    const double thr = mean + 3.0 * sqrt(var);
#pragma unroll
    for (int i = 0; i < 32; ++i) {
      const bool bit = (m >> i) & 1u;
      const float ai = bit ? 0.0f : fabsf(cur[i]);
      if ((double)ai > thr) m |= (1u << i);
    }

    // outlier dynamic scale via identity: newly-masked max == A iff A > thr
    const float O = ((double)A > thr) ? fmaxf(Bm, A) : Bm;
    const float os = fmaxf(O, 1e-8f) / 127.0f;

    // ---- quantize + store (single divide per element: paths are disjoint) ----
    if (valid) {
#pragma unroll
      for (int k = 0; k < 8; ++k) {
        float o4[4];
#pragma unroll
        for (int j = 0; j < 4; ++j) {
          const int i = k * 4 + j;
          const bool mm = (m >> i) & 1u;
          const float d = mm ? os : sv;
          const float bound = mm ? 127.0f : 7.0f;
          float q = rintf(cur[i] / d);
          q = fminf(fmaxf(q, -bound), bound);
          o4[j] = q * d;
        }
        *(float4*)(y + base + (size_t)r * D_DIM + k * 256) =
            make_float4(o4[0], o4[1], o4[2], o4[3]);
      }
    }

#pragma unroll
    for (int i = 0; i < 32; ++i) cur[i] = nxt[i];
  }
}

// ---------------- fallback: exact sequential, runs only if speculation failed ----------------
__device__ __forceinline__ void grid_barrier(uint* cnt, uint* gen) {
  __syncthreads();
  if (threadIdx.x == 0) {
    const uint my = __hip_atomic_load(gen, __ATOMIC_ACQUIRE, __HIP_MEMORY_SCOPE_AGENT);
    const uint old = __hip_atomic_fetch_add(cnt, 1u, __ATOMIC_ACQ_REL, __HIP_MEMORY_SCOPE_AGENT);
    if (old == FB_NBLK - 1) {
      __hip_atomic_store(cnt, 0u, __ATOMIC_RELAXED, __HIP_MEMORY_SCOPE_AGENT);
      __hip_atomic_store(gen, my + 1u, __ATOMIC_RELEASE, __HIP_MEMORY_SCOPE_AGENT);
    } else {
      while (__hip_atomic_load(gen, __ATOMIC_ACQUIRE, __HIP_MEMORY_SCOPE_AGENT) == my)
        __builtin_amdgcn_s_sleep(8);
    }
  }
  __syncthreads();
}

__global__ __launch_bounds__(256, 2) void qact_fallback(
    const float* __restrict__ x, const float* __restrict__ s, float* __restrict__ y,
    const uint* __restrict__ flagset, uint* __restrict__ flags2, uint* __restrict__ bar) {
  // If every speculative flag came out 1, speculation was exact (induction) -> done.
  bool ok = true;
#pragma unroll
  for (int r = 0; r < R_STEPS; ++r) ok &= (flagset[r * 32] != 0u);
  if (ok) return;

  __shared__ float redM[4];
  __shared__ double redS[4][2];
  __shared__ float redO[4];

  const int tid = threadIdx.x, lane = tid & 63, wid = tid >> 6;
  u64 mask = 0;  // 7 rows x 8 bits

  for (int r = 0; r < R_STEPS; ++r) {
    // ---- phase A: exact flag contributions with current masks ----
    for (int j = 0; j < 7; ++j) {
      const int row = blockIdx.x + FB_NBLK * j;
      if (row >= NROWS) break;  // block-uniform
      const int b = row / G_TOK, g = row % G_TOK;
      const int tok = g * R_STEPS + r;
      float A = 0.0f;
      if (tok < L_TOK) {
        const size_t off = ((size_t)b * L_TOK + tok) * D_DIM + (size_t)tid * 8;
        float v[8];
        load8(v, x + off);
        const uint mj = (uint)(mask >> (j * 8)) & 0xffu;
#pragma unroll
        for (int i = 0; i < 8; ++i)
          if (!((mj >> i) & 1u)) A = fmaxf(A, fabsf(v[i]));
      }
#pragma unroll
      for (int o = 32; o > 0; o >>= 1) A = fmaxf(A, __shfl_down(A, o, 64));
      if (lane == 0) redM[wid] = A;
      __syncthreads();
      A = fmaxf(fmaxf(redM[0], redM[1]), fmaxf(redM[2], redM[3]));
      const float sv = (tok < L_TOK) ? s[tok] : 1.0f;
      if (tid == 0 && A / 7.0f > sv) atomicOr(&flags2[r * 32], 1u);
      __syncthreads();
    }

    grid_barrier(&bar[0], &bar[1]);

    const uint f = __hip_atomic_load(&flags2[r * 32], __ATOMIC_ACQUIRE, __HIP_MEMORY_SCOPE_AGENT);

    // ---- phase B: mask update (if f), quantize, store ----
    for (int j = 0; j < 7; ++j) {
      const int row = blockIdx.x + FB_NBLK * j;
      if (row >= NROWS) break;
      const int b = row / G_TOK, g = row % G_TOK;
      const int tok = g * R_STEPS + r;
      const bool valid = tok < L_TOK;
      const size_t off = ((size_t)b * L_TOK + (valid ? tok : 0)) * D_DIM + (size_t)tid * 8;
      float v[8];
      if (valid) load8(v, x + off);
      else zero8(v);
      uint mj = (uint)(mask >> (j * 8)) & 0xffu;
      float a[8];
#pragma unroll
      for (int i = 0; i < 8; ++i) a[i] = ((mj >> i) & 1u) ? 0.0f : fabsf(v[i]);
      if (f) {  // grid-uniform
        double S1 = 0.0, S2 = 0.0;
#pragma unroll
        for (int i = 0; i < 8; ++i) {
          S1 += (double)a[i];
          S2 += (double)a[i] * (double)a[i];
        }
#pragma unroll
        for (int o = 32; o > 0; o >>= 1) {
          S1 += __shfl_down(S1, o, 64);
          S2 += __shfl_down(S2, o, 64);
        }
        if (lane == 0) { redS[wid][0] = S1; redS[wid][1] = S2; }
        __syncthreads();
        S1 = redS[0][0] + redS[1][0] + redS[2][0] + redS[3][0];
        S2 = redS[0][1] + redS[1][1] + redS[2][1] + redS[3][1];
        const double n = (double)D_DIM;
        const double mean = S1 / n;
        double var = (S2 - n * mean * mean) / (n - 1.0);
        var = var > 0.0 ? var : 0.0;
        const double thr = mean + 3.0 * sqrt(var);
#pragma unroll
        for (int i = 0; i < 8; ++i)
          if ((double)a[i] > thr) mj |= (1u << i);
        mask = (mask & ~((u64)0xffu << (j * 8))) | ((u64)mj << (j * 8));
        __syncthreads();
      }
      if (valid) {
        float O = 0.0f;
#pragma unroll
        for (int i = 0; i < 8; ++i)
          if ((mj >> i) & 1u) O = fmaxf(O, fabsf(v[i]));
#pragma unroll
        for (int o = 32; o > 0; o >>= 1) O = fmaxf(O, __shfl_down(O, o, 64));
        if (lane == 0) redO[wid] = O;
        __syncthreads();
        O = fmaxf(fmaxf(redO[0], redO[1]), fmaxf(redO[2], redO[3]));
        const float os = fmaxf(O, 1e-8f) / 127.0f;
        const float sv = s[tok];
        float out[8];
#pragma unroll
        for (int i = 0; i < 8; ++i) {
          const bool mm = (mj >> i) & 1u;
          const float inl = mm ? 0.0f : v[i];
          const float orr = mm ? v[i] : 0.0f;
          const float qi = fminf(fmaxf(rintf(inl / sv), -7.0f), 7.0f);
          const float qo = fminf(fmaxf(rintf(orr / os), -127.0f), 127.0f);
          out[i] = qi * sv + qo * os;
        }
        store8(y + off, out);
        __syncthreads();
      }
    }
  }
}

extern "C" void kernel_launch(void* const* d_in, const int* in_sizes, int n_in,
                              void* d_out, int out_size, void* d_ws, size_t ws_size,
                              hipStream_t stream) {
  const float* x = (const float*)d_in[0];
  const float* s = (const float*)d_in[1];
  float* y = (float*)d_out;
  uint* flagset = (uint*)d_ws;
  uint* flags2 = (uint*)((char*)d_ws + 2048);
  uint* bar = (uint*)((char*)d_ws + 3968);

  (void)hipMemsetAsync(d_ws, 0, 4096, stream);
  qact_spec<<<NROWS / 4, 256, 0, stream>>>(x, s, y, flagset);
  qact_fallback<<<FB_NBLK, 256, 0, stream>>>(x, s, y, flagset, flags2, bar);
}

// Round 14
// 79.259 us; speedup vs baseline: 1.0987x; 1.0987x over previous
//
#include <hip/hip_runtime.h>

#define L_TOK 4096
#define D_DIM 2048
#define R_STEPS 10
#define G_TOK 410
#define NROWS 1640
#define FB_NBLK 256

typedef unsigned int uint;
typedef unsigned long long u64;
typedef float f32x4 __attribute__((ext_vector_type(4)));

// ws layout (bytes), zeroed each call:
// [0,1280)     flagset[r*32]  (speculative kernel's computed flags, stride 128B)
// [2048,3328)  flags2[r*32]   (fallback's exact flags)
// [3968,3976)  barrier {count, generation}

__device__ __forceinline__ void load8(float* v, const float* p) {
  float4 a = *(const float4*)p;
  float4 b = *(const float4*)(p + 4);
  v[0] = a.x; v[1] = a.y; v[2] = a.z; v[3] = a.w;
  v[4] = b.x; v[5] = b.y; v[6] = b.z; v[7] = b.w;
}
__device__ __forceinline__ void zero8(float* v) {
#pragma unroll
  for (int i = 0; i < 8; ++i) v[i] = 0.0f;
}
__device__ __forceinline__ void store8(float* p, const float* v) {
  *(float4*)p = make_float4(v[0], v[1], v[2], v[3]);
  *(float4*)(p + 4) = make_float4(v[4], v[5], v[6], v[7]);
}
// nontemporal: y is write-once never-read; no-allocate keeps x L3-resident
// (134MB x + 134MB y > 256MB L3 otherwise -> 66MB/replay x re-fetch).
// NOTE: R5's apparent NT pathology was a confounded spill (VGPR 32); this is
// the clean A/B at VGPR ~40.
__device__ __forceinline__ void store8_nt(float* p, const float* v) {
  f32x4 w0 = {v[0], v[1], v[2], v[3]};
  f32x4 w1 = {v[4], v[5], v[6], v[7]};
  __builtin_nontemporal_store(w0, (f32x4*)p);
  __builtin_nontemporal_store(w1, (f32x4*)(p + 4));
}

// ---------------- speculative kernel: assume every step's flag == 1 ----------------
__global__ __launch_bounds__(256, 4) void qact_spec(
    const float* __restrict__ x, const float* __restrict__ s,
    float* __restrict__ y, uint* __restrict__ flagset) {
  __shared__ float redA[2][4], redB[2][4];
  __shared__ double redS[2][4][2];

  const int tid = threadIdx.x, lane = tid & 63, wid = tid >> 6;
  const int row = blockIdx.x;
  const int b = row / G_TOK, g = row % G_TOK;
  const size_t base = ((size_t)b * L_TOK + (size_t)g * R_STEPS) * D_DIM + (size_t)tid * 8;

  uint m = 0;  // this thread's 8 outlier-mask bits (carried across steps)
  float cur[8], nxt[8];
  load8(cur, x + base);  // token g*10 always < 4096

  for (int r = 0; r < R_STEPS; ++r) {
    const int tok = g * R_STEPS + r;
    const bool valid = tok < L_TOK;  // block-uniform
    const int buf = r & 1;           // double-buffered shared (one sync per step)
    const float sv = valid ? s[tok] : 1.0f;

    // prefetch next token slab (independent of mask state) — hides HBM latency
    if (r + 1 < R_STEPS) {
      if (tok + 1 < L_TOK) load8(nxt, x + base + (size_t)(r + 1) * D_DIM);
      else zero8(nxt);
    }

    // ---- single fused reduction pass ----
    // A  = max |x| over OLD-unmasked (for flag + newly-masked max)
    // Bm = max |x| over OLD-masked   (for outlier scale)
    // S1,S2 = fp64 sums of a, a^2 over OLD-unmasked (for mean/std)
    float a[8];
    float A = 0.0f, Bm = 0.0f;
    double S1 = 0.0, S2 = 0.0;
#pragma unroll
    for (int i = 0; i < 8; ++i) {
      const bool bit = (m >> i) & 1u;
      const float fa = fabsf(cur[i]);
      a[i] = bit ? 0.0f : fa;
      A = fmaxf(A, a[i]);
      Bm = bit ? fmaxf(Bm, fa) : Bm;
      const double ad = (double)a[i];
      S1 += ad;
      S2 += ad * ad;
    }
#pragma unroll
    for (int o = 32; o > 0; o >>= 1) {
      A = fmaxf(A, __shfl_down(A, o, 64));
      Bm = fmaxf(Bm, __shfl_down(Bm, o, 64));
      S1 += __shfl_down(S1, o, 64);
      S2 += __shfl_down(S2, o, 64);
    }
    if (lane == 0) {
      redA[buf][wid] = A; redB[buf][wid] = Bm;
      redS[buf][wid][0] = S1; redS[buf][wid][1] = S2;
    }
    __syncthreads();
    A = fmaxf(fmaxf(redA[buf][0], redA[buf][1]), fmaxf(redA[buf][2], redA[buf][3]));
    Bm = fmaxf(fmaxf(redB[buf][0], redB[buf][1]), fmaxf(redB[buf][2], redB[buf][3]));
    S1 = redS[buf][0][0] + redS[buf][1][0] + redS[buf][2][0] + redS[buf][3][0];
    S2 = redS[buf][0][1] + redS[buf][1][1] + redS[buf][2][1] + redS[buf][3][1];

    if (tid == 0) {
      if (A / 7.0f > sv) atomicOr(&flagset[r * 32], 1u);  // record exact contribution
    }

    // ---- mask update under flag=1 assumption: a > mean + 3*std(ddof=1) ----
    const double n = (double)D_DIM;
    const double mean = S1 / n;
    double var = (S2 - n * mean * mean) / (n - 1.0);
    var = var > 0.0 ? var : 0.0;
    const double thr = mean + 3.0 * sqrt(var);
#pragma unroll
    for (int i = 0; i < 8; ++i)
      if ((double)a[i] > thr) m |= (1u << i);

    // outlier dynamic scale via identity: newly-masked max == A iff A > thr
    const float O = ((double)A > thr) ? fmaxf(Bm, A) : Bm;
    const float os = fmaxf(O, 1e-8f) / 127.0f;

    // ---- quantize + store (single divide per element: paths are disjoint) ----
    if (valid) {
      float out[8];
#pragma unroll
      for (int i = 0; i < 8; ++i) {
        const bool mm = (m >> i) & 1u;
        const float d = mm ? os : sv;
        const float bound = mm ? 127.0f : 7.0f;
        float q = rintf(cur[i] / d);
        q = fminf(fmaxf(q, -bound), bound);
        out[i] = q * d;
      }
      store8_nt(y + base + (size_t)r * D_DIM, out);
    }

#pragma unroll
    for (int i = 0; i < 8; ++i) cur[i] = nxt[i];
  }
}

// ---------------- fallback: exact sequential, runs only if speculation failed ----------------
__device__ __forceinline__ void grid_barrier(uint* cnt, uint* gen) {
  __syncthreads();
  if (threadIdx.x == 0) {
    const uint my = __hip_atomic_load(gen, __ATOMIC_ACQUIRE, __HIP_MEMORY_SCOPE_AGENT);
    const uint old = __hip_atomic_fetch_add(cnt, 1u, __ATOMIC_ACQ_REL, __HIP_MEMORY_SCOPE_AGENT);
    if (old == FB_NBLK - 1) {
      __hip_atomic_store(cnt, 0u, __ATOMIC_RELAXED, __HIP_MEMORY_SCOPE_AGENT);
      __hip_atomic_store(gen, my + 1u, __ATOMIC_RELEASE, __HIP_MEMORY_SCOPE_AGENT);
    } else {
      while (__hip_atomic_load(gen, __ATOMIC_ACQUIRE, __HIP_MEMORY_SCOPE_AGENT) == my)
        __builtin_amdgcn_s_sleep(8);
    }
  }
  __syncthreads();
}

__global__ __launch_bounds__(256, 2) void qact_fallback(
    const float* __restrict__ x, const float* __restrict__ s, float* __restrict__ y,
    const uint* __restrict__ flagset, uint* __restrict__ flags2, uint* __restrict__ bar) {
  // If every speculative flag came out 1, speculation was exact (induction) -> done.
  bool ok = true;
#pragma unroll
  for (int r = 0; r < R_STEPS; ++r) ok &= (flagset[r * 32] != 0u);
  if (ok) return;

  __shared__ float redM[4];
  __shared__ double redS[4][2];
  __shared__ float redO[4];

  const int tid = threadIdx.x, lane = tid & 63, wid = tid >> 6;
  u64 mask = 0;  // 7 rows x 8 bits

  for (int r = 0; r < R_STEPS; ++r) {
    // ---- phase A: exact flag contributions with current masks ----
    for (int j = 0; j < 7; ++j) {
      const int row = blockIdx.x + FB_NBLK * j;
      if (row >= NROWS) break;  // block-uniform
      const int b = row / G_TOK, g = row % G_TOK;
      const int tok = g * R_STEPS + r;
      float A = 0.0f;
      if (tok < L_TOK) {
        const size_t off = ((size_t)b * L_TOK + tok) * D_DIM + (size_t)tid * 8;
        float v[8];
        load8(v, x + off);
        const uint mj = (uint)(mask >> (j * 8)) & 0xffu;
#pragma unroll
        for (int i = 0; i < 8; ++i)
          if (!((mj >> i) & 1u)) A = fmaxf(A, fabsf(v[i]));
      }
#pragma unroll
      for (int o = 32; o > 0; o >>= 1) A = fmaxf(A, __shfl_down(A, o, 64));
      if (lane == 0) redM[wid] = A;
      __syncthreads();
      A = fmaxf(fmaxf(redM[0], redM[1]), fmaxf(redM[2], redM[3]));
      const float sv = (tok < L_TOK) ? s[tok] : 1.0f;
      if (tid == 0 && A / 7.0f > sv) atomicOr(&flags2[r * 32], 1u);
      __syncthreads();
    }

    grid_barrier(&bar[0], &bar[1]);

    const uint f = __hip_atomic_load(&flags2[r * 32], __ATOMIC_ACQUIRE, __HIP_MEMORY_SCOPE_AGENT);

    // ---- phase B: mask update (if f), quantize, store ----
    for (int j = 0; j < 7; ++j) {
      const int row = blockIdx.x + FB_NBLK * j;
      if (row >= NROWS) break;
      const int b = row / G_TOK, g = row % G_TOK;
      const int tok = g * R_STEPS + r;
      const bool valid = tok < L_TOK;
      const size_t off = ((size_t)b * L_TOK + (valid ? tok : 0)) * D_DIM + (size_t)tid * 8;
      float v[8];
      if (valid) load8(v, x + off);
      else zero8(v);
      uint mj = (uint)(mask >> (j * 8)) & 0xffu;
      float a[8];
#pragma unroll
      for (int i = 0; i < 8; ++i) a[i] = ((mj >> i) & 1u) ? 0.0f : fabsf(v[i]);
      if (f) {  // grid-uniform
        double S1 = 0.0, S2 = 0.0;
#pragma unroll
        for (int i = 0; i < 8; ++i) {
          S1 += (double)a[i];
          S2 += (double)a[i] * (double)a[i];
        }
#pragma unroll
        for (int o = 32; o > 0; o >>= 1) {
          S1 += __shfl_down(S1, o, 64);
          S2 += __shfl_down(S2, o, 64);
        }
        if (lane == 0) { redS[wid][0] = S1; redS[wid][1] = S2; }
        __syncthreads();
        S1 = redS[0][0] + redS[1][0] + redS[2][0] + redS[3][0];
        S2 = redS[0][1] + redS[1][1] + redS[2][1] + redS[3][1];
        const double n = (double)D_DIM;
        const double mean = S1 / n;
        double var = (S2 - n * mean * mean) / (n - 1.0);
        var = var > 0.0 ? var : 0.0;
        const double thr = mean + 3.0 * sqrt(var);
#pragma unroll
        for (int i = 0; i < 8; ++i)
          if ((double)a[i] > thr) mj |= (1u << i);
        mask = (mask & ~((u64)0xffu << (j * 8))) | ((u64)mj << (j * 8));
        __syncthreads();
      }
      if (valid) {
        float O = 0.0f;
#pragma unroll
        for (int i = 0; i < 8; ++i)
          if ((mj >> i) & 1u) O = fmaxf(O, fabsf(v[i]));
#pragma unroll
        for (int o = 32; o > 0; o >>= 1) O = fmaxf(O, __shfl_down(O, o, 64));
        if (lane == 0) redO[wid] = O;
        __syncthreads();
        O = fmaxf(fmaxf(redO[0], redO[1]), fmaxf(redO[2], redO[3]));
        const float os = fmaxf(O, 1e-8f) / 127.0f;
        const float sv = s[tok];
        float out[8];
#pragma unroll
        for (int i = 0; i < 8; ++i) {
          const bool mm = (mj >> i) & 1u;
          const float inl = mm ? 0.0f : v[i];
          const float orr = mm ? v[i] : 0.0f;
          const float qi = fminf(fmaxf(rintf(inl / sv), -7.0f), 7.0f);
          const float qo = fminf(fmaxf(rintf(orr / os), -127.0f), 127.0f);
          out[i] = qi * sv + qo * os;
        }
        store8(y + off, out);
        __syncthreads();
      }
    }
  }
}

extern "C" void kernel_launch(void* const* d_in, const int* in_sizes, int n_in,
                              void* d_out, int out_size, void* d_ws, size_t ws_size,
                              hipStream_t stream) {
  const float* x = (const float*)d_in[0];
  const float* s = (const float*)d_in[1];
  float* y = (float*)d_out;
  uint* flagset = (uint*)d_ws;
  uint* flags2 = (uint*)((char*)d_ws + 2048);
  uint* bar = (uint*)((char*)d_ws + 3968);

  (void)hipMemsetAsync(d_ws, 0, 4096, stream);
  qact_spec<<<NROWS, 256, 0, stream>>>(x, s, y, flagset);
  qact_fallback<<<FB_NBLK, 256, 0, stream>>>(x, s, y, flagset, flags2, bar);
}